// Round 3
// baseline (72.679 us; speedup 1.0000x reference)
//
#include <hip/hip_runtime.h>
#include <math.h>

// Problem constants (from reference setup_inputs)
constexpr int B  = 2;
constexpr int Lq = 4096;
constexpr int Lk = 4096;
constexpr int H  = 8;
constexpr int C  = 64;
constexpr int K  = 32;
constexpr float INV_SCALE = 0.125f;
constexpr int HC = H * C;   // 512 floats row stride in key/value

// One wave = 4 query rows; each 16-lane GROUP owns one full row.
//   g  = lane>>4 : which row of the wave's 4
//   c4 = lane&15 : float4 channel slot (channels [4*c4, 4*c4+4))
// Per key i (0..31): group loads K-row (16 lanes x float4 = 256 B),
// dot + 4-step 16-lane butterfly; score parked in lane (i&15) (2 regs).
// Softmax: 4-step 16-lane reduce on 2 values. PV: broadcast attn_i
// (1 bpermute) + V gather + 4 fma. No cross-group epilogue reduce.
// XCD pinning: group = bid&15 = (b*H+h) => same (b,h) on same XCD,
// its 2 MB K+V set lives in that XCD's 4 MB L2.
__global__ __launch_bounds__(256) void topk_attn_kernel(
    const float* __restrict__ query,
    const float* __restrict__ key,
    const float* __restrict__ value,
    const int*   __restrict__ pos,
    float*       __restrict__ out)
{
    const int bid    = blockIdx.x;          // 0..4095
    const int group  = bid & 15;            // b*H + h
    const int lchunk = bid >> 4;            // 0..255
    const int wave   = threadIdx.x >> 6;
    const int lane   = threadIdx.x & 63;
    const int g      = lane >> 4;           // row within wave
    const int c4     = lane & 15;           // float4 slot

    const int b = group >> 3;
    const int h = group & 7;
    const int l = lchunk * 16 + wave * 4 + g;   // 0..4095

    const size_t row  = ((size_t)(b * Lq + l) * H + h);
    const size_t qoff = row * (size_t)C;

    float4 q4 = *(const float4*)(query + qoff + 4 * c4);
    q4.x *= INV_SCALE; q4.y *= INV_SCALE; q4.z *= INV_SCALE; q4.w *= INV_SCALE;

    // lane holds pos[2*c4], pos[2*c4+1] of its group's row
    const int2 pp = *(const int2*)(pos + row * (size_t)K + 2 * c4);

    const float* kbase = key   + (size_t)b * Lk * HC + (size_t)h * C;
    const float* vbase = value + (size_t)b * Lk * HC + (size_t)h * C;
    const int gbase = g << 4;

    // ---- phase A: scores; lane c4 ends with s0 = score[c4], s1 = score[c4+16]
    float s0 = 0.0f, s1 = 0.0f;
    #pragma unroll
    for (int i = 0; i < K; ++i) {
        const int pk = __shfl((i & 1) ? pp.y : pp.x, gbase + (i >> 1));
        const float4 kv = *(const float4*)(kbase + pk * HC + 4 * c4);
        float t = q4.x * kv.x;
        t = fmaf(q4.y, kv.y, t);
        t = fmaf(q4.z, kv.z, t);
        t = fmaf(q4.w, kv.w, t);
        #pragma unroll
        for (int m = 8; m >= 1; m >>= 1) t += __shfl_xor(t, m);
        if (c4 == (i & 15)) { if (i < 16) s0 = t; else s1 = t; }
    }

    // ---- softmax over the 32 keys (16-lane reduce, 2 values/lane) ----
    float mx = fmaxf(s0, s1);
    #pragma unroll
    for (int m = 8; m >= 1; m >>= 1) mx = fmaxf(mx, __shfl_xor(mx, m));
    float e0 = __expf(s0 - mx);
    float e1 = __expf(s1 - mx);
    float se = e0 + e1;
    #pragma unroll
    for (int m = 8; m >= 1; m >>= 1) se += __shfl_xor(se, m);
    const float inv = 1.0f / se;
    e0 *= inv; e1 *= inv;     // lane c4 holds attn[c4], attn[c4+16]

    // ---- phase B: out = sum_i attn_i * V_i ----
    float4 acc = make_float4(0.f, 0.f, 0.f, 0.f);
    #pragma unroll
    for (int i = 0; i < K; ++i) {
        const int pk = __shfl((i & 1) ? pp.y : pp.x, gbase + (i >> 1));
        const float a  = __shfl((i < 16) ? e0 : e1, gbase + (i & 15));
        const float4 v4 = *(const float4*)(vbase + pk * HC + 4 * c4);
        acc.x = fmaf(a, v4.x, acc.x);
        acc.y = fmaf(a, v4.y, acc.y);
        acc.z = fmaf(a, v4.z, acc.z);
        acc.w = fmaf(a, v4.w, acc.w);
    }

    *(float4*)(out + qoff + 4 * c4) = acc;
}

extern "C" void kernel_launch(void* const* d_in, const int* in_sizes, int n_in,
                              void* d_out, int out_size, void* d_ws, size_t ws_size,
                              hipStream_t stream) {
    const float* query = (const float*)d_in[0];
    const float* key   = (const float*)d_in[1];
    const float* value = (const float*)d_in[2];
    const int*   pos   = (const int*)d_in[3];
    float* out = (float*)d_out;

    const int total_rows = B * Lq * H;      // 65536
    const int blocks = total_rows / 16;     // 4096 (4 waves x 4 rows each)
    topk_attn_kernel<<<blocks, 256, 0, stream>>>(query, key, value, pos, out);
}

// Round 4
// 56.488 us; speedup vs baseline: 1.2866x; 1.2866x over previous
//
#include <hip/hip_runtime.h>
#include <math.h>

// Problem constants (from reference setup_inputs)
constexpr int B  = 2;
constexpr int Lq = 4096;
constexpr int Lk = 4096;
constexpr int H  = 8;
constexpr int C  = 64;
constexpr int K  = 32;
constexpr float INV_SCALE = 0.125f;
constexpr int HC = H * C;   // 512 floats row stride in key/value

// One wave = 2 query rows (l0, l0+1) of the same (b,h).
// Wave split into 4 groups of 16 lanes:
//   g  = lane>>4 : key sub-group — group g handles keys {4i+g, i=0..7} of BOTH rows
//   c4 = lane&15 : float4 channel slot
// Per lane: 16 K-gathers + 16 V-gathers, offsets precomputed from one pos
// read — two independent dot/reduce chains per step for latency hiding.
// XCD pinning: group = bid&15 = (b*H+h) => same (b,h) stays on one XCD,
// its 2 MB K+V set lives in that XCD's 4 MB L2.
__global__ __launch_bounds__(256) void topk_attn_kernel(
    const float* __restrict__ query,
    const float* __restrict__ key,
    const float* __restrict__ value,
    const int*   __restrict__ pos,
    float*       __restrict__ out)
{
    const int bid    = blockIdx.x;          // 0..8191
    const int group  = bid & 15;            // b*H + h
    const int lchunk = bid >> 4;            // 0..511
    const int wave   = threadIdx.x >> 6;
    const int lane   = threadIdx.x & 63;
    const int g      = lane >> 4;           // 0..3
    const int c4     = lane & 15;           // 0..15

    const int b = group >> 3;
    const int h = group & 7;
    const int l0 = lchunk * 8 + wave * 2;   // rows l0 and l0+1

    const size_t row0 = ((size_t)(b * Lq + l0) * H + h);
    const size_t row1 = row0 + H;           // (l0+1) same h
    const size_t qoff0 = row0 * (size_t)C;
    const size_t qoff1 = row1 * (size_t)C;

    float4 qa = *(const float4*)(query + qoff0 + 4 * c4);
    float4 qb = *(const float4*)(query + qoff1 + 4 * c4);
    qa.x *= INV_SCALE; qa.y *= INV_SCALE; qa.z *= INV_SCALE; qa.w *= INV_SCALE;
    qb.x *= INV_SCALE; qb.y *= INV_SCALE; qb.z *= INV_SCALE; qb.w *= INV_SCALE;

    const int pa = pos[row0 * K + (lane & 31)];
    const int pb = pos[row1 * K + (lane & 31)];

    const float* kbase = key   + (size_t)b * Lk * HC + (size_t)h * C;
    const float* vbase = value + (size_t)b * Lk * HC + (size_t)h * C;

    // gather offsets (shared by K and V), all known up-front
    int offA[8], offB[8];
    #pragma unroll
    for (int i = 0; i < 8; ++i) {
        offA[i] = __shfl(pa, 4 * i + g) * HC + 4 * c4;
        offB[i] = __shfl(pb, 4 * i + g) * HC + 4 * c4;
    }

    // ---- phase A: scores (two independent chains) ----
    float sA[8], sB[8];
    #pragma unroll
    for (int i = 0; i < 8; ++i) {
        const float4 ka = *(const float4*)(kbase + offA[i]);
        const float4 kb = *(const float4*)(kbase + offB[i]);
        float tA = qa.x * ka.x;
        float tB = qb.x * kb.x;
        tA = fmaf(qa.y, ka.y, tA);  tB = fmaf(qb.y, kb.y, tB);
        tA = fmaf(qa.z, ka.z, tA);  tB = fmaf(qb.z, kb.z, tB);
        tA = fmaf(qa.w, ka.w, tA);  tB = fmaf(qb.w, kb.w, tB);
        #pragma unroll
        for (int m = 8; m >= 1; m >>= 1) {
            tA += __shfl_xor(tA, m);
            tB += __shfl_xor(tB, m);
        }
        sA[i] = tA; sB[i] = tB;
    }

    // ---- softmax (each row: local 8 + cross-group masks 16,32) ----
    float mxA = sA[0], mxB = sB[0];
    #pragma unroll
    for (int i = 1; i < 8; ++i) { mxA = fmaxf(mxA, sA[i]); mxB = fmaxf(mxB, sB[i]); }
    mxA = fmaxf(mxA, __shfl_xor(mxA, 16)); mxB = fmaxf(mxB, __shfl_xor(mxB, 16));
    mxA = fmaxf(mxA, __shfl_xor(mxA, 32)); mxB = fmaxf(mxB, __shfl_xor(mxB, 32));

    float seA = 0.0f, seB = 0.0f;
    #pragma unroll
    for (int i = 0; i < 8; ++i) {
        sA[i] = __expf(sA[i] - mxA); seA += sA[i];
        sB[i] = __expf(sB[i] - mxB); seB += sB[i];
    }
    seA += __shfl_xor(seA, 16); seB += __shfl_xor(seB, 16);
    seA += __shfl_xor(seA, 32); seB += __shfl_xor(seB, 32);
    const float invA = 1.0f / seA;
    const float invB = 1.0f / seB;

    // ---- phase B: PV ----
    float4 accA = make_float4(0.f, 0.f, 0.f, 0.f);
    float4 accB = make_float4(0.f, 0.f, 0.f, 0.f);
    #pragma unroll
    for (int i = 0; i < 8; ++i) {
        const float aA = sA[i] * invA;
        const float aB = sB[i] * invB;
        const float4 va = *(const float4*)(vbase + offA[i]);
        const float4 vb = *(const float4*)(vbase + offB[i]);
        accA.x = fmaf(aA, va.x, accA.x);  accB.x = fmaf(aB, vb.x, accB.x);
        accA.y = fmaf(aA, va.y, accA.y);  accB.y = fmaf(aB, vb.y, accB.y);
        accA.z = fmaf(aA, va.z, accA.z);  accB.z = fmaf(aB, vb.z, accB.z);
        accA.w = fmaf(aA, va.w, accA.w);  accB.w = fmaf(aB, vb.w, accB.w);
    }
    // combine the 4 key-groups for each row
    #pragma unroll
    for (int m = 16; m <= 32; m <<= 1) {
        accA.x += __shfl_xor(accA.x, m);  accB.x += __shfl_xor(accB.x, m);
        accA.y += __shfl_xor(accA.y, m);  accB.y += __shfl_xor(accB.y, m);
        accA.z += __shfl_xor(accA.z, m);  accB.z += __shfl_xor(accB.z, m);
        accA.w += __shfl_xor(accA.w, m);  accB.w += __shfl_xor(accB.w, m);
    }

    if (g == 0) *(float4*)(out + qoff0 + 4 * c4) = accA;
    if (g == 1) *(float4*)(out + qoff1 + 4 * c4) = accB;
}

extern "C" void kernel_launch(void* const* d_in, const int* in_sizes, int n_in,
                              void* d_out, int out_size, void* d_ws, size_t ws_size,
                              hipStream_t stream) {
    const float* query = (const float*)d_in[0];
    const float* key   = (const float*)d_in[1];
    const float* value = (const float*)d_in[2];
    const int*   pos   = (const int*)d_in[3];
    float* out = (float*)d_out;

    const int total_rows = B * Lq * H;      // 65536
    const int blocks = total_rows / 8;      // 8192 (4 waves x 2 rows each)
    topk_attn_kernel<<<blocks, 256, 0, stream>>>(query, key, value, pos, out);
}

// Round 5
// 53.164 us; speedup vs baseline: 1.3671x; 1.0625x over previous
//
#include <hip/hip_runtime.h>
#include <math.h>

// Problem constants (from reference setup_inputs)
constexpr int B  = 2;
constexpr int Lq = 4096;
constexpr int Lk = 4096;
constexpr int H  = 8;
constexpr int C  = 64;
constexpr int K  = 32;
constexpr float INV_SCALE = 0.125f;
constexpr int HC = H * C;                 // 512 elements: row stride in key/value
constexpr int NKV = B * Lk * H * C;       // 4,194,304 elements per array

typedef _Float16 half4_t __attribute__((ext_vector_type(4)));

// ---------------- prepass: fp32 K,V -> fp16 in d_ws (streamed) ----------------
__global__ __launch_bounds__(256) void convert_kv_f16(
    const float* __restrict__ key,
    const float* __restrict__ value,
    _Float16*    __restrict__ kh,
    _Float16*    __restrict__ vh)
{
    const int n4 = NKV / 4;               // float4 chunks per array
    for (int i = blockIdx.x * blockDim.x + threadIdx.x;
         i < 2 * n4; i += gridDim.x * blockDim.x) {
        if (i < n4) {
            const float4 v = ((const float4*)key)[i];
            half4_t h = { (_Float16)v.x, (_Float16)v.y, (_Float16)v.z, (_Float16)v.w };
            ((half4_t*)kh)[i] = h;
        } else {
            const float4 v = ((const float4*)value)[i - n4];
            half4_t h = { (_Float16)v.x, (_Float16)v.y, (_Float16)v.z, (_Float16)v.w };
            ((half4_t*)vh)[i - n4] = h;
        }
    }
}

// ---------------- main: R2 structure, fp16 gathers (8 B/lane) ----------------
// One wave per query row; 4 groups of 16 lanes; group g handles keys {4i+g}.
// A 16-lane group's half4 loads cover one 128 B K/V row = one cache line.
// XCD pinning: group = bid&15 = (b*H+h); fp16 K+V set per (b,h) is 1 MB,
// two groups per XCD -> 2 MB resident in that XCD's 4 MB L2.
__global__ __launch_bounds__(256) void topk_attn_f16(
    const float*    __restrict__ query,
    const _Float16* __restrict__ keyh,
    const _Float16* __restrict__ valh,
    const int*      __restrict__ pos,
    float*          __restrict__ out)
{
    const int bid    = blockIdx.x;        // 0..16383
    const int group  = bid & 15;          // b*H + h
    const int lchunk = bid >> 4;          // 0..1023
    const int wave   = threadIdx.x >> 6;
    const int lane   = threadIdx.x & 63;
    const int g      = lane >> 4;
    const int c4     = lane & 15;

    const int b = group >> 3;
    const int h = group & 7;
    const int l = lchunk * 4 + wave;

    const size_t row  = ((size_t)(b * Lq + l) * H + h);
    const size_t qoff = row * (size_t)C;

    float4 q4 = *(const float4*)(query + qoff + 4 * c4);
    q4.x *= INV_SCALE; q4.y *= INV_SCALE; q4.z *= INV_SCALE; q4.w *= INV_SCALE;

    const int p = pos[row * (size_t)K + (lane & 31)];

    const _Float16* kbase = keyh + (size_t)b * Lk * HC + (size_t)h * C;
    const _Float16* vbase = valh + (size_t)b * Lk * HC + (size_t)h * C;

    int off[8];
    #pragma unroll
    for (int i = 0; i < 8; ++i)
        off[i] = __shfl(p, 4 * i + g) * HC + 4 * c4;

    // ---- scores ----
    float s[8];
    #pragma unroll
    for (int i = 0; i < 8; ++i) {
        const half4_t kv = *(const half4_t*)(kbase + off[i]);
        float t = q4.x * (float)kv.x;
        t = fmaf(q4.y, (float)kv.y, t);
        t = fmaf(q4.z, (float)kv.z, t);
        t = fmaf(q4.w, (float)kv.w, t);
        #pragma unroll
        for (int m = 8; m >= 1; m >>= 1) t += __shfl_xor(t, m);
        s[i] = t;
    }

    // ---- softmax over 32 keys ----
    float mx = s[0];
    #pragma unroll
    for (int i = 1; i < 8; ++i) mx = fmaxf(mx, s[i]);
    mx = fmaxf(mx, __shfl_xor(mx, 16));
    mx = fmaxf(mx, __shfl_xor(mx, 32));

    float se = 0.0f;
    #pragma unroll
    for (int i = 0; i < 8; ++i) { s[i] = __expf(s[i] - mx); se += s[i]; }
    se += __shfl_xor(se, 16);
    se += __shfl_xor(se, 32);
    const float inv = 1.0f / se;

    // ---- PV ----
    float4 acc = make_float4(0.f, 0.f, 0.f, 0.f);
    #pragma unroll
    for (int i = 0; i < 8; ++i) {
        const float a = s[i] * inv;
        const half4_t v4 = *(const half4_t*)(vbase + off[i]);
        acc.x = fmaf(a, (float)v4.x, acc.x);
        acc.y = fmaf(a, (float)v4.y, acc.y);
        acc.z = fmaf(a, (float)v4.z, acc.z);
        acc.w = fmaf(a, (float)v4.w, acc.w);
    }
    #pragma unroll
    for (int m = 16; m <= 32; m <<= 1) {
        acc.x += __shfl_xor(acc.x, m);
        acc.y += __shfl_xor(acc.y, m);
        acc.z += __shfl_xor(acc.z, m);
        acc.w += __shfl_xor(acc.w, m);
    }

    if (g == 0) *(float4*)(out + qoff + 4 * c4) = acc;
}

// ---------------- fallback: proven R2 fp32 kernel (if ws too small) ----------
__global__ __launch_bounds__(256) void topk_attn_f32(
    const float* __restrict__ query,
    const float* __restrict__ key,
    const float* __restrict__ value,
    const int*   __restrict__ pos,
    float*       __restrict__ out)
{
    const int bid    = blockIdx.x;
    const int group  = bid & 15;
    const int lchunk = bid >> 4;
    const int wave   = threadIdx.x >> 6;
    const int lane   = threadIdx.x & 63;
    const int g      = lane >> 4;
    const int c4     = lane & 15;

    const int b = group >> 3;
    const int h = group & 7;
    const int l = lchunk * 4 + wave;

    const size_t row  = ((size_t)(b * Lq + l) * H + h);
    const size_t qoff = row * (size_t)C;

    float4 q4 = *(const float4*)(query + qoff + 4 * c4);
    q4.x *= INV_SCALE; q4.y *= INV_SCALE; q4.z *= INV_SCALE; q4.w *= INV_SCALE;

    const int p = pos[row * (size_t)K + (lane & 31)];

    const float* kbase = key   + (size_t)b * Lk * HC + (size_t)h * C;
    const float* vbase = value + (size_t)b * Lk * HC + (size_t)h * C;

    int off[8];
    #pragma unroll
    for (int i = 0; i < 8; ++i)
        off[i] = __shfl(p, 4 * i + g) * HC + 4 * c4;

    float s[8];
    #pragma unroll
    for (int i = 0; i < 8; ++i) {
        const float4 kv = *(const float4*)(kbase + off[i]);
        float t = q4.x * kv.x;
        t = fmaf(q4.y, kv.y, t);
        t = fmaf(q4.z, kv.z, t);
        t = fmaf(q4.w, kv.w, t);
        #pragma unroll
        for (int m = 8; m >= 1; m >>= 1) t += __shfl_xor(t, m);
        s[i] = t;
    }

    float mx = s[0];
    #pragma unroll
    for (int i = 1; i < 8; ++i) mx = fmaxf(mx, s[i]);
    mx = fmaxf(mx, __shfl_xor(mx, 16));
    mx = fmaxf(mx, __shfl_xor(mx, 32));

    float se = 0.0f;
    #pragma unroll
    for (int i = 0; i < 8; ++i) { s[i] = __expf(s[i] - mx); se += s[i]; }
    se += __shfl_xor(se, 16);
    se += __shfl_xor(se, 32);
    const float inv = 1.0f / se;

    float4 acc = make_float4(0.f, 0.f, 0.f, 0.f);
    #pragma unroll
    for (int i = 0; i < 8; ++i) {
        const float a = s[i] * inv;
        const float4 v4 = *(const float4*)(vbase + off[i]);
        acc.x = fmaf(a, v4.x, acc.x);
        acc.y = fmaf(a, v4.y, acc.y);
        acc.z = fmaf(a, v4.z, acc.z);
        acc.w = fmaf(a, v4.w, acc.w);
    }
    #pragma unroll
    for (int m = 16; m <= 32; m <<= 1) {
        acc.x += __shfl_xor(acc.x, m);
        acc.y += __shfl_xor(acc.y, m);
        acc.z += __shfl_xor(acc.z, m);
        acc.w += __shfl_xor(acc.w, m);
    }

    if (g == 0) *(float4*)(out + qoff + 4 * c4) = acc;
}

extern "C" void kernel_launch(void* const* d_in, const int* in_sizes, int n_in,
                              void* d_out, int out_size, void* d_ws, size_t ws_size,
                              hipStream_t stream) {
    const float* query = (const float*)d_in[0];
    const float* key   = (const float*)d_in[1];
    const float* value = (const float*)d_in[2];
    const int*   pos   = (const int*)d_in[3];
    float* out = (float*)d_out;

    const int total_rows = B * Lq * H;          // 65536
    const int blocks = total_rows / 4;          // 16384 (4 waves/block)

    const size_t need = (size_t)2 * NKV * sizeof(_Float16);  // 16.8 MB
    if (ws_size >= need && d_ws != nullptr) {
        _Float16* kh = (_Float16*)d_ws;
        _Float16* vh = kh + NKV;
        convert_kv_f16<<<2048, 256, 0, stream>>>(key, value, kh, vh);
        topk_attn_f16<<<blocks, 256, 0, stream>>>(query, kh, vh, pos, out);
    } else {
        topk_attn_f32<<<blocks, 256, 0, stream>>>(query, key, value, pos, out);
    }
}

// Round 7
// 47.260 us; speedup vs baseline: 1.5379x; 1.1249x over previous
//
#include <hip/hip_runtime.h>
#include <math.h>

// Problem constants (from reference setup_inputs)
constexpr int B  = 2;
constexpr int Lq = 4096;
constexpr int Lk = 4096;
constexpr int H  = 8;
constexpr int C  = 64;
constexpr int K  = 32;
constexpr float INV_SCALE = 0.125f;
constexpr int HC = H * C;                 // 512 elements: row stride in key/value
constexpr int NKV = B * Lk * H * C;       // 4,194,304 elements per array

typedef _Float16 h2 __attribute__((ext_vector_type(2)));
typedef _Float16 half4_t __attribute__((ext_vector_type(4)));

static __device__ __forceinline__ h2 pack_h2(float lo, float hi) {
    return __builtin_bit_cast(h2, __builtin_amdgcn_cvt_pkrtz(lo, hi));
}

#if __has_builtin(__builtin_amdgcn_fdot2)
static __device__ __forceinline__ float fdot2(h2 a, h2 b, float c) {
    return __builtin_amdgcn_fdot2(a, b, c, false);
}
#else
static __device__ __forceinline__ float fdot2(h2 a, h2 b, float c) {
    return c + (float)a.x * (float)b.x + (float)a.y * (float)b.y;
}
#endif

static __device__ __forceinline__ h2 shfl_h2_xor(h2 v, int m) {
    int i = __builtin_bit_cast(int, v);
    i = __shfl_xor(i, m);
    return __builtin_bit_cast(h2, i);
}

// ---------------- prepass: fp32 K,V -> fp16 in d_ws (streamed) ----------------
__global__ __launch_bounds__(256) void convert_kv_f16(
    const float* __restrict__ key,
    const float* __restrict__ value,
    _Float16*    __restrict__ kh,
    _Float16*    __restrict__ vh)
{
    const int n4 = NKV / 4;               // float4 chunks per array
    for (int i = blockIdx.x * blockDim.x + threadIdx.x;
         i < 2 * n4; i += gridDim.x * blockDim.x) {
        if (i < n4) {
            const float4 v = ((const float4*)key)[i];
            half4_t h = { (_Float16)v.x, (_Float16)v.y, (_Float16)v.z, (_Float16)v.w };
            ((half4_t*)kh)[i] = h;
        } else {
            const float4 v = ((const float4*)value)[i - n4];
            half4_t h = { (_Float16)v.x, (_Float16)v.y, (_Float16)v.z, (_Float16)v.w };
            ((half4_t*)vh)[i - n4] = h;
        }
    }
}

// ---------------- main: 8-lane groups, packed fp16 math ----------------
// One wave per query row. 8 groups of 8 lanes:
//   g  = lane>>3 : group g handles keys {4g..4g+3}
//   c8 = lane&7  : channels [8*c8, 8*c8+8)  (16 B of an fp16 row)
// K/V gather: one dwordx4 per key per lane (8-lane group = full 128 B row).
// Score: 4x v_dot2_f32_f16 + 3-step reduce (masks 1,2,4).
// Softmax: 4 scores/lane + cross-group masks 8,16,32.
// PV: packed fp16 fma (4 sequential adds/lane), fp16 tree reduce.
// XCD pinning: group = bid&15 = (b*H+h); fp16 K+V per (b,h) = 1 MB,
// 2 groups/XCD -> 2 MB resident in that XCD's 4 MB L2.
__global__ __launch_bounds__(256) void topk_attn_f16(
    const float*    __restrict__ query,
    const _Float16* __restrict__ keyh,
    const _Float16* __restrict__ valh,
    const int*      __restrict__ pos,
    float*          __restrict__ out)
{
    const int bid    = blockIdx.x;        // 0..16383
    const int group  = bid & 15;          // b*H + h
    const int lchunk = bid >> 4;          // 0..1023
    const int wave   = threadIdx.x >> 6;
    const int lane   = threadIdx.x & 63;
    const int g      = lane >> 3;         // 0..7
    const int c8     = lane & 7;          // 0..7

    const int b = group >> 3;
    const int h = group & 7;
    const int l = lchunk * 4 + wave;

    const size_t row  = ((size_t)(b * Lq + l) * H + h);
    const size_t qoff = row * (size_t)C;

    // q channels [8c8, 8c8+8), pre-scaled, packed to 4x half2
    const float4 qa = *(const float4*)(query + qoff + 8 * c8);
    const float4 qb = *(const float4*)(query + qoff + 8 * c8 + 4);
    h2 qp[4];
    qp[0] = pack_h2(qa.x * INV_SCALE, qa.y * INV_SCALE);
    qp[1] = pack_h2(qa.z * INV_SCALE, qa.w * INV_SCALE);
    qp[2] = pack_h2(qb.x * INV_SCALE, qb.y * INV_SCALE);
    qp[3] = pack_h2(qb.z * INV_SCALE, qb.w * INV_SCALE);

    const int p = pos[row * (size_t)K + (lane & 31)];

    const _Float16* kbase = keyh + (size_t)b * Lk * HC + (size_t)h * C;
    const _Float16* vbase = valh + (size_t)b * Lk * HC + (size_t)h * C;

    // gather offsets for this group's 4 keys (shared by K and V)
    int off[4];
    #pragma unroll
    for (int i = 0; i < 4; ++i)
        off[i] = __shfl(p, 4 * g + i) * HC + 8 * c8;

    // ---- scores: s[i] = score of key 4g+i, replicated within the group ----
    float s[4];
    #pragma unroll
    for (int i = 0; i < 4; ++i) {
        const uint4 kv = *(const uint4*)(kbase + off[i]);
        float t = fdot2(qp[0], __builtin_bit_cast(h2, kv.x), 0.0f);
        t = fdot2(qp[1], __builtin_bit_cast(h2, kv.y), t);
        t = fdot2(qp[2], __builtin_bit_cast(h2, kv.z), t);
        t = fdot2(qp[3], __builtin_bit_cast(h2, kv.w), t);
        #pragma unroll
        for (int m = 4; m >= 1; m >>= 1) t += __shfl_xor(t, m);
        s[i] = t;
    }

    // ---- softmax over all 32 keys ----
    float mx = fmaxf(fmaxf(s[0], s[1]), fmaxf(s[2], s[3]));
    mx = fmaxf(mx, __shfl_xor(mx, 8));
    mx = fmaxf(mx, __shfl_xor(mx, 16));
    mx = fmaxf(mx, __shfl_xor(mx, 32));

    float se = 0.0f;
    #pragma unroll
    for (int i = 0; i < 4; ++i) { s[i] = __expf(s[i] - mx); se += s[i]; }
    se += __shfl_xor(se, 8);
    se += __shfl_xor(se, 16);
    se += __shfl_xor(se, 32);
    const float inv = 1.0f / se;

    h2 a2[4];
    #pragma unroll
    for (int i = 0; i < 4; ++i) {
        const float a = s[i] * inv;
        a2[i] = pack_h2(a, a);
    }

    // ---- PV: packed fp16 accumulate over this group's 4 keys ----
    h2 acc[4] = { h2{0,0}, h2{0,0}, h2{0,0}, h2{0,0} };
    #pragma unroll
    for (int i = 0; i < 4; ++i) {
        const uint4 vv = *(const uint4*)(vbase + off[i]);
        acc[0] = a2[i] * __builtin_bit_cast(h2, vv.x) + acc[0];
        acc[1] = a2[i] * __builtin_bit_cast(h2, vv.y) + acc[1];
        acc[2] = a2[i] * __builtin_bit_cast(h2, vv.z) + acc[2];
        acc[3] = a2[i] * __builtin_bit_cast(h2, vv.w) + acc[3];
    }
    // cross-group tree reduce (masks 8,16,32) in packed fp16
    #pragma unroll
    for (int m = 8; m <= 32; m <<= 1) {
        #pragma unroll
        for (int j = 0; j < 4; ++j)
            acc[j] = acc[j] + shfl_h2_xor(acc[j], m);
    }

    if (g == 0) {
        const float4 o0 = make_float4((float)acc[0].x, (float)acc[0].y,
                                      (float)acc[1].x, (float)acc[1].y);
        const float4 o1 = make_float4((float)acc[2].x, (float)acc[2].y,
                                      (float)acc[3].x, (float)acc[3].y);
        *(float4*)(out + qoff + 8 * c8)     = o0;
        *(float4*)(out + qoff + 8 * c8 + 4) = o1;
    }
}

// ---------------- fallback: proven R2 fp32 kernel (if ws too small) ----------
__global__ __launch_bounds__(256) void topk_attn_f32(
    const float* __restrict__ query,
    const float* __restrict__ key,
    const float* __restrict__ value,
    const int*   __restrict__ pos,
    float*       __restrict__ out)
{
    const int bid    = blockIdx.x;
    const int group  = bid & 15;
    const int lchunk = bid >> 4;
    const int wave   = threadIdx.x >> 6;
    const int lane   = threadIdx.x & 63;
    const int g      = lane >> 4;
    const int c4     = lane & 15;

    const int b = group >> 3;
    const int h = group & 7;
    const int l = lchunk * 4 + wave;

    const size_t row  = ((size_t)(b * Lq + l) * H + h);
    const size_t qoff = row * (size_t)C;

    float4 q4 = *(const float4*)(query + qoff + 4 * c4);
    q4.x *= INV_SCALE; q4.y *= INV_SCALE; q4.z *= INV_SCALE; q4.w *= INV_SCALE;

    const int p = pos[row * (size_t)K + (lane & 31)];

    const float* kbase = key   + (size_t)b * Lk * HC + (size_t)h * C;
    const float* vbase = value + (size_t)b * Lk * HC + (size_t)h * C;

    int off[8];
    #pragma unroll
    for (int i = 0; i < 8; ++i)
        off[i] = __shfl(p, 4 * i + g) * HC + 4 * c4;

    float s[8];
    #pragma unroll
    for (int i = 0; i < 8; ++i) {
        const float4 kv = *(const float4*)(kbase + off[i]);
        float t = q4.x * kv.x;
        t = fmaf(q4.y, kv.y, t);
        t = fmaf(q4.z, kv.z, t);
        t = fmaf(q4.w, kv.w, t);
        #pragma unroll
        for (int m = 8; m >= 1; m >>= 1) t += __shfl_xor(t, m);
        s[i] = t;
    }

    float mx = s[0];
    #pragma unroll
    for (int i = 1; i < 8; ++i) mx = fmaxf(mx, s[i]);
    mx = fmaxf(mx, __shfl_xor(mx, 16));
    mx = fmaxf(mx, __shfl_xor(mx, 32));

    float se = 0.0f;
    #pragma unroll
    for (int i = 0; i < 8; ++i) { s[i] = __expf(s[i] - mx); se += s[i]; }
    se += __shfl_xor(se, 16);
    se += __shfl_xor(se, 32);
    const float inv = 1.0f / se;

    float4 acc = make_float4(0.f, 0.f, 0.f, 0.f);
    #pragma unroll
    for (int i = 0; i < 8; ++i) {
        const float a = s[i] * inv;
        const float4 v4 = *(const float4*)(vbase + off[i]);
        acc.x = fmaf(a, v4.x, acc.x);
        acc.y = fmaf(a, v4.y, acc.y);
        acc.z = fmaf(a, v4.z, acc.z);
        acc.w = fmaf(a, v4.w, acc.w);
    }
    #pragma unroll
    for (int m = 16; m <= 32; m <<= 1) {
        acc.x += __shfl_xor(acc.x, m);
        acc.y += __shfl_xor(acc.y, m);
        acc.z += __shfl_xor(acc.z, m);
        acc.w += __shfl_xor(acc.w, m);
    }

    if (g == 0) *(float4*)(out + qoff + 4 * c4) = acc;
}

extern "C" void kernel_launch(void* const* d_in, const int* in_sizes, int n_in,
                              void* d_out, int out_size, void* d_ws, size_t ws_size,
                              hipStream_t stream) {
    const float* query = (const float*)d_in[0];
    const float* key   = (const float*)d_in[1];
    const float* value = (const float*)d_in[2];
    const int*   pos   = (const int*)d_in[3];
    float* out = (float*)d_out;

    const int total_rows = B * Lq * H;          // 65536
    const int blocks = total_rows / 4;          // 16384 (4 waves/block)

    const size_t need = (size_t)2 * NKV * sizeof(_Float16);  // 16.8 MB
    if (ws_size >= need && d_ws != nullptr) {
        _Float16* kh = (_Float16*)d_ws;
        _Float16* vh = kh + NKV;
        convert_kv_f16<<<2048, 256, 0, stream>>>(key, value, kh, vh);
        topk_attn_f16<<<blocks, 256, 0, stream>>>(query, kh, vh, pos, out);
    } else {
        topk_attn_f32<<<blocks, 256, 0, stream>>>(query, key, value, pos, out);
    }
}